// Round 11
// baseline (104.720 us; speedup 1.0000x reference)
//
#include <hip/hip_runtime.h>

// Problem: x [64, 512, 512, 3] f32.  out = clip((mean_c(x) - q10)/max(q90-q10, .01), 0, 1)
// B=64, HW=262144 px/batch. 3 kernels + memset. x (201 MB) FITS IN L3 (256 MB):
//   K1: hist-only — stream x, channel mean -> u32 LDS hist -> global u32 hist.
//       (no xm intermediate; 4 independent pixel streams for MLP)
//   K2: per-batch quantiles from 8192-bin hist (register-resident)
//   K3: re-read x (L3-resident by now), recompute mean, normalize, NT-store out.

#define BINS 8192
#define PIXB 262144
#define NB 16                      // chunks per batch -> 1024 blocks
#define CHUNK (PIXB / NB)          // 16384 px per block
#define QTR (CHUNK / 4)            // 4096 px per stream

typedef float vf4 __attribute__((ext_vector_type(4)));   // native vec for NT store

// ---------------- K1: channel-mean + histogram (no store) ----------------
__global__ __launch_bounds__(256) void k_mean_hist(const float* __restrict__ x,
                                                   unsigned int* __restrict__ histg) {
    __shared__ unsigned int hist[BINS];        // full u32 counts, 32 KB
    const int tid = threadIdx.x;
    const int b = blockIdx.x / NB;
    const int c = blockIdx.x % NB;

    for (int i = tid; i < BINS; i += 256) hist[i] = 0;
    __syncthreads();

    const float4* __restrict__ X4 = (const float4*)x;
    const int pix0 = b * PIXB + c * CHUNK;
    const float k3 = 1.0f / 3.0f;

    for (int it = 0; it < QTR / 1024; ++it) {   // 4 iters, 4 streams x 4 px
        const int pA = pix0 + it * 1024 + tid * 4;
        const int fA = (pA * 3) >> 2;
        const int fB = ((pA + QTR) * 3) >> 2;
        const int fC = ((pA + 2 * QTR) * 3) >> 2;
        const int fD = ((pA + 3 * QTR) * 3) >> 2;
        // 12 independent float4 loads -> all in flight together
        float4 a0 = X4[fA + 0];
        float4 a1 = X4[fA + 1];
        float4 a2 = X4[fA + 2];
        float4 b0 = X4[fB + 0];
        float4 b1 = X4[fB + 1];
        float4 b2 = X4[fB + 2];
        float4 c0 = X4[fC + 0];
        float4 c1 = X4[fC + 1];
        float4 c2 = X4[fC + 2];
        float4 d0 = X4[fD + 0];
        float4 d1 = X4[fD + 1];
        float4 d2 = X4[fD + 2];

        float s[16];
        s[0]  = (a0.x + a0.y + a0.z) * k3;
        s[1]  = (a0.w + a1.x + a1.y) * k3;
        s[2]  = (a1.z + a1.w + a2.x) * k3;
        s[3]  = (a2.y + a2.z + a2.w) * k3;
        s[4]  = (b0.x + b0.y + b0.z) * k3;
        s[5]  = (b0.w + b1.x + b1.y) * k3;
        s[6]  = (b1.z + b1.w + b2.x) * k3;
        s[7]  = (b2.y + b2.z + b2.w) * k3;
        s[8]  = (c0.x + c0.y + c0.z) * k3;
        s[9]  = (c0.w + c1.x + c1.y) * k3;
        s[10] = (c1.z + c1.w + c2.x) * k3;
        s[11] = (c2.y + c2.z + c2.w) * k3;
        s[12] = (d0.x + d0.y + d0.z) * k3;
        s[13] = (d0.w + d1.x + d1.y) * k3;
        s[14] = (d1.z + d1.w + d2.x) * k3;
        s[15] = (d2.y + d2.z + d2.w) * k3;
#pragma unroll
        for (int j = 0; j < 16; ++j) {
            int bin = min(BINS - 1, max(0, (int)(s[j] * (float)BINS)));
            atomicAdd(&hist[bin], 1u);
        }
    }
    __syncthreads();

    unsigned int* dst = histg + (size_t)b * BINS;
    for (int i = tid; i < BINS; i += 256) {
        unsigned int v = hist[i];
        if (v) atomicAdd(&dst[i], v);          // device-scope
    }
}

// ---------------- K2: per-batch quantiles from histogram ----------------
__global__ __launch_bounds__(256) void k_quantile(const unsigned int* __restrict__ histg,
                                                  float* __restrict__ lo_inv) {
    __shared__ unsigned int tsum[256];
    __shared__ float vals[4];
    const int b = blockIdx.x;
    const int tid = threadIdx.x;

    const uint4* __restrict__ H4 = (const uint4*)(histg + (size_t)b * BINS);
    uint4 hh[8];                               // bins [tid*32, tid*32+32)
#pragma unroll
    for (int j = 0; j < 8; ++j) hh[j] = H4[tid * 8 + j];
    unsigned int s = 0;
#pragma unroll
    for (int j = 0; j < 8; ++j) s += hh[j].x + hh[j].y + hh[j].z + hh[j].w;
    tsum[tid] = s;
    __syncthreads();
    for (int off = 1; off < 256; off <<= 1) {  // Hillis-Steele inclusive scan
        unsigned int v = tsum[tid];
        unsigned int add = (tid >= off) ? tsum[tid - off] : 0u;
        __syncthreads();
        tsum[tid] = v + add;
        __syncthreads();
    }
    unsigned int cum = (tid == 0) ? 0u : tsum[tid - 1];

    // order stats q*(n-1), n=262144: 26214.3 -> {26214,26215}, 235928.7 -> {235928,235929}
    const unsigned int T0 = 26214u, T1 = 26215u, T2 = 235928u, T3 = 235929u;
    const int base = tid * 32;
#pragma unroll
    for (int j = 0; j < 8; ++j) {
        unsigned int e4[4] = {hh[j].x, hh[j].y, hh[j].z, hh[j].w};
#pragma unroll
        for (int q = 0; q < 4; ++q) {
            unsigned int h = e4[q];
            unsigned int nc = cum + h;
            if (h) {
                float edge = (float)(base + 4 * j + q);
                float invh = 1.0f / (float)h;
#define CHECK(KT, slot)                                                     \
                if (KT >= cum && KT < nc) {                                 \
                    float r = (float)(KT - cum);                            \
                    vals[slot] = (edge + (r + 0.5f) * invh) * (1.0f / BINS);\
                }
                CHECK(T0, 0) CHECK(T1, 1) CHECK(T2, 2) CHECK(T3, 3)
#undef CHECK
            }
            cum = nc;
        }
    }
    __syncthreads();
    if (tid == 0) {
        float lo = 0.7f * vals[0] + 0.3f * vals[1];
        float hi = 0.3f * vals[2] + 0.7f * vals[3];
        float rng = fmaxf(hi - lo, 0.01f);
        lo_inv[b * 2 + 0] = lo;
        lo_inv[b * 2 + 1] = 1.0f / rng;
    }
}

// ---------------- K3: re-read x (L3-hot), recompute mean, normalize ----------------
__global__ __launch_bounds__(256) void k_norm(const float* __restrict__ x,
                                              float* __restrict__ out,
                                              const float* __restrict__ lo_inv) {
    const int t = blockIdx.x * 256 + threadIdx.x;   // 8 px/thread
    const int pA = t * 8;
    const int b = pA >> 18;                         // 262144 px/batch
    const float lo = lo_inv[b * 2 + 0];
    const float inv = lo_inv[b * 2 + 1];
    const float k3 = 1.0f / 3.0f;

    const float4* __restrict__ X4 = (const float4*)x;
    const int f = (pA * 3) >> 2;                    // 6 consecutive float4
    float4 a0 = X4[f + 0];
    float4 a1 = X4[f + 1];
    float4 a2 = X4[f + 2];
    float4 a3 = X4[f + 3];
    float4 a4 = X4[f + 4];
    float4 a5 = X4[f + 5];

    vf4 v0, v1;
    v0.x = fminf(fmaxf(((a0.x + a0.y + a0.z) * k3 - lo) * inv, 0.0f), 1.0f);
    v0.y = fminf(fmaxf(((a0.w + a1.x + a1.y) * k3 - lo) * inv, 0.0f), 1.0f);
    v0.z = fminf(fmaxf(((a1.z + a1.w + a2.x) * k3 - lo) * inv, 0.0f), 1.0f);
    v0.w = fminf(fmaxf(((a2.y + a2.z + a2.w) * k3 - lo) * inv, 0.0f), 1.0f);
    v1.x = fminf(fmaxf(((a3.x + a3.y + a3.z) * k3 - lo) * inv, 0.0f), 1.0f);
    v1.y = fminf(fmaxf(((a3.w + a4.x + a4.y) * k3 - lo) * inv, 0.0f), 1.0f);
    v1.z = fminf(fmaxf(((a4.z + a4.w + a5.x) * k3 - lo) * inv, 0.0f), 1.0f);
    v1.w = fminf(fmaxf(((a5.y + a5.z + a5.w) * k3 - lo) * inv, 0.0f), 1.0f);

    vf4* __restrict__ O4 = (vf4*)out;
    // non-temporal: out is write-once -> don't evict x from L2/L3
    __builtin_nontemporal_store(v0, &O4[t * 2 + 0]);
    __builtin_nontemporal_store(v1, &O4[t * 2 + 1]);
}

extern "C" void kernel_launch(void* const* d_in, const int* in_sizes, int n_in,
                              void* d_out, int out_size, void* d_ws, size_t ws_size,
                              hipStream_t stream) {
    const float* x = (const float*)d_in[0];
    float* out = (float*)d_out;

    // ws layout: [0,512B) lo_inv | [4KB, 4KB+2MB) histg
    float* lo_inv = (float*)d_ws;
    unsigned int* histg = (unsigned int*)((char*)d_ws + 4096);

    (void)hipMemsetAsync(histg, 0, (size_t)64 * BINS * sizeof(unsigned int), stream);

    k_mean_hist<<<64 * NB, 256, 0, stream>>>(x, histg);
    k_quantile<<<64, 256, 0, stream>>>(histg, lo_inv);
    k_norm<<<out_size / (8 * 256), 256, 0, stream>>>(x, out, lo_inv);
}